// Round 1
// baseline (1346.724 us; speedup 1.0000x reference)
//
#include <hip/hip_runtime.h>
#include <hip/hip_bf16.h>
#include <cstddef>

// Problem constants
#define D_MODEL 256
#define NHEAD   8
#define HDIM    32
#define NLEV    3
#define NPNT    4
#define DFF     1024
#define BATCH   8
#define LQ      3600
#define LIN     4725   // 60*60 + 30*30 + 15*15
#define MROWS   (BATCH*LQ)   // 28800

// ---------------------------------------------------------------------------
// Transpose tgt (LQ,B,D) -> x0 (B,LQ,D), float4 granularity
__global__ __launch_bounds__(256) void transpose_in_kernel(
    const float* __restrict__ tgt, float* __restrict__ x0)
{
    int vid = blockIdx.x * 256 + threadIdx.x;     // 0 .. B*LQ*64
    int d4   = vid & 63;                          // float4 index within row
    int rest = vid >> 6;                          // b*LQ + lq
    int lq   = rest % LQ;
    int b    = rest / LQ;
    float4 v = ((const float4*)tgt)[(size_t)(lq * BATCH + b) * 64 + d4];
    ((float4*)x0)[(size_t)rest * 64 + d4] = v;
}

// ---------------------------------------------------------------------------
// Precompute query_pos @ W^T for in_proj (768), samp_off (192), attn_w (96)
__global__ void qp_proj_kernel(const float* __restrict__ qp,
                               const float* __restrict__ w_in,
                               const float* __restrict__ w_so,
                               const float* __restrict__ w_aw,
                               float* __restrict__ outv)
{
    int o = blockIdx.x * blockDim.x + threadIdx.x;
    if (o >= 768 + 192 + 96) return;
    const float* wrow;
    if (o < 768)       wrow = w_in + (size_t)o * D_MODEL;
    else if (o < 960)  wrow = w_so + (size_t)(o - 768) * D_MODEL;
    else               wrow = w_aw + (size_t)(o - 960) * D_MODEL;
    float acc = 0.f;
    for (int d = 0; d < D_MODEL; ++d) acc += qp[d] * wrow[d];
    outv[o] = acc;
}

// ---------------------------------------------------------------------------
// Tiled fp32 GEMM: C[m,n] = act( sum_k A[m,k]*W[n,k] + bias[n] + (n<b2lim ? bias2[n]:0) )
// BM=BN=64, BK=16, 256 threads, 4x4 microtile.
#define BM 64
#define BN 64
#define BK 16
__global__ __launch_bounds__(256) void gemm_tn(
    const float* __restrict__ A,   // M x K
    const float* __restrict__ W,   // N x K
    const float* __restrict__ bias,
    const float* __restrict__ bias2, int b2lim,
    float* __restrict__ C,         // M x N
    int M, int N, int K, int relu)
{
    __shared__ __align__(16) float As[BK][BM + 4];
    __shared__ __align__(16) float Ws[BK][BN + 4];

    const int tid = threadIdx.x;
    const int tm = (tid >> 4) << 2;     // 0..60
    const int tn = (tid & 15) << 2;     // 0..60
    const int lr = tid >> 2;            // 0..63 (tile row to load)
    const int lc = (tid & 3) << 2;      // 0,4,8,12 (k offset)

    const int m0 = blockIdx.x * BM;
    const int n0 = blockIdx.y * BN;

    const int am = m0 + lr;
    const int wn = n0 + lr;
    const bool avalid = (am < M);
    const bool wvalid = (wn < N);
    const float* Arow = A + (size_t)am * K + lc;
    const float* Wrow = W + (size_t)wn * K + lc;

    float acc[4][4] = {};

    for (int k0 = 0; k0 < K; k0 += BK) {
        float4 av = avalid ? *(const float4*)(Arow + k0) : make_float4(0.f,0.f,0.f,0.f);
        float4 wv = wvalid ? *(const float4*)(Wrow + k0) : make_float4(0.f,0.f,0.f,0.f);
        As[lc + 0][lr] = av.x; As[lc + 1][lr] = av.y;
        As[lc + 2][lr] = av.z; As[lc + 3][lr] = av.w;
        Ws[lc + 0][lr] = wv.x; Ws[lc + 1][lr] = wv.y;
        Ws[lc + 2][lr] = wv.z; Ws[lc + 3][lr] = wv.w;
        __syncthreads();
#pragma unroll
        for (int k = 0; k < BK; ++k) {
            const float4 a = *(const float4*)&As[k][tm];
            const float4 w = *(const float4*)&Ws[k][tn];
            acc[0][0] += a.x * w.x; acc[0][1] += a.x * w.y; acc[0][2] += a.x * w.z; acc[0][3] += a.x * w.w;
            acc[1][0] += a.y * w.x; acc[1][1] += a.y * w.y; acc[1][2] += a.y * w.z; acc[1][3] += a.y * w.w;
            acc[2][0] += a.z * w.x; acc[2][1] += a.z * w.y; acc[2][2] += a.z * w.z; acc[2][3] += a.z * w.w;
            acc[3][0] += a.w * w.x; acc[3][1] += a.w * w.y; acc[3][2] += a.w * w.z; acc[3][3] += a.w * w.w;
        }
        __syncthreads();
    }

#pragma unroll
    for (int i = 0; i < 4; ++i) {
        const int m = m0 + tm + i;
        if (m >= M) continue;
#pragma unroll
        for (int j = 0; j < 4; ++j) {
            const int n = n0 + tn + j;
            if (n >= N) continue;
            float v = acc[i][j];
            if (bias)  v += bias[n];
            if (bias2 && n < b2lim) v += bias2[n];
            if (relu)  v = fmaxf(v, 0.f);
            C[(size_t)m * N + n] = v;
        }
    }
}

// ---------------------------------------------------------------------------
// Self-attention over S=8 (batch axis), per (n=lq): logits (8 heads,8,8),
// softmax over t, ctx. qkv layout: [m = s*LQ + n][768] (q:0-255, k:256-511, v:512-767)
__global__ __launch_bounds__(256) void self_attn_kernel(
    const float* __restrict__ qkv, float* __restrict__ ctx)
{
    __shared__ float sh[8][768];
    __shared__ float ls[8][8][8];   // [h][s][t]
    const int n = blockIdx.x;
    const int t = threadIdx.x;
#pragma unroll
    for (int s = 0; s < 8; ++s) {
        const float* row = qkv + (size_t)(s * LQ + n) * 768;
        sh[s][t]       = row[t];
        sh[s][t + 256] = row[t + 256];
        sh[s][t + 512] = row[t + 512];
    }
    __syncthreads();
    const int h = t >> 5, j = t & 31;
#pragma unroll
    for (int pair = j; pair < 64; pair += 32) {
        const int s = pair >> 3, tt = pair & 7;
        float acc = 0.f;
#pragma unroll
        for (int d = 0; d < 32; ++d)
            acc += sh[s][h * 32 + d] * sh[tt][256 + h * 32 + d];
        ls[h][s][tt] = acc * 0.17677669529663687f;  // 1/sqrt(32)
    }
    __syncthreads();
    if (t < 64) {
        const int hh = t >> 3, s = t & 7;
        float mx = -1e30f;
        for (int tt = 0; tt < 8; ++tt) mx = fmaxf(mx, ls[hh][s][tt]);
        float sum = 0.f;
        for (int tt = 0; tt < 8; ++tt) { float e = expf(ls[hh][s][tt] - mx); ls[hh][s][tt] = e; sum += e; }
        const float inv = 1.f / sum;
        for (int tt = 0; tt < 8; ++tt) ls[hh][s][tt] *= inv;
    }
    __syncthreads();
#pragma unroll
    for (int s = 0; s < 8; ++s) {
        float acc = 0.f;
#pragma unroll
        for (int tt = 0; tt < 8; ++tt)
            acc += ls[h][s][tt] * sh[tt][512 + h * 32 + j];
        ctx[(size_t)(s * LQ + n) * D_MODEL + h * 32 + j] = acc;
    }
}

// ---------------------------------------------------------------------------
// out[row] = LN( x[m] + y[m] ) * g + b ; swap: out row = (lq*B + b) else m.
// One wave per row, 4 rows per block.
__global__ __launch_bounds__(256) void add_ln_kernel(
    const float* __restrict__ x, const float* __restrict__ y,
    const float* __restrict__ g, const float* __restrict__ bb,
    float* __restrict__ out, int swap)
{
    const int w = threadIdx.x >> 6, lane = threadIdx.x & 63;
    const int m = blockIdx.x * 4 + w;
    const float4 xv = ((const float4*)(x + (size_t)m * D_MODEL))[lane];
    const float4 yv = ((const float4*)(y + (size_t)m * D_MODEL))[lane];
    const float v0 = xv.x + yv.x, v1 = xv.y + yv.y, v2 = xv.z + yv.z, v3 = xv.w + yv.w;
    float s1 = v0 + v1 + v2 + v3;
    float s2 = v0 * v0 + v1 * v1 + v2 * v2 + v3 * v3;
#pragma unroll
    for (int o = 1; o < 64; o <<= 1) {
        s1 += __shfl_xor(s1, o);
        s2 += __shfl_xor(s2, o);
    }
    const float mean = s1 * (1.f / 256.f);
    const float var  = s2 * (1.f / 256.f) - mean * mean;
    const float inv  = rsqrtf(var + 1e-5f);
    const float4 gv = ((const float4*)g)[lane];
    const float4 bv = ((const float4*)bb)[lane];
    float4 o4;
    o4.x = (v0 - mean) * inv * gv.x + bv.x;
    o4.y = (v1 - mean) * inv * gv.y + bv.y;
    o4.z = (v2 - mean) * inv * gv.z + bv.z;
    o4.w = (v3 - mean) * inv * gv.w + bv.w;
    size_t orow = (size_t)m;
    if (swap) orow = (size_t)(m % LQ) * BATCH + (m / LQ);
    ((float4*)out)[orow * 64 + lane] = o4;
}

// ---------------------------------------------------------------------------
// Deformable sampling. One block per (b,lq); thread = (h = tid/32, hd = tid%32).
__device__ __forceinline__ float ms_sample(const float* vbase, int s0, int Wl, int Hl,
                                           int yi, int xi, float w)
{
    const bool valid = (xi >= 0) & (xi < Wl) & (yi >= 0) & (yi < Hl);
    const int xc = min(max(xi, 0), Wl - 1);
    const int yc = min(max(yi, 0), Hl - 1);
    const float v = vbase[(size_t)(s0 + yc * Wl + xc) * D_MODEL];
    return valid ? v * w : 0.f;
}

__global__ __launch_bounds__(256) void msdeform_kernel(
    const float* __restrict__ value,   // [b*LIN + lin][h*32+hd]
    const float* __restrict__ off,     // [m][192]
    const float* __restrict__ awr,     // [m][96]
    float* __restrict__ out)           // [m][256]
{
    const int m  = blockIdx.x;
    const int b  = m / LQ;
    const int lq = m % LQ;
    const int h    = threadIdx.x >> 5;
    const int lane = threadIdx.x & 31;

    // softmax over 12 attention weights for this (m,h)
    const float* awp = awr + (size_t)m * 96 + h * 12;
    float myv = (lane < 12) ? awp[lane] : -1e30f;
    float mx = myv;
#pragma unroll
    for (int o = 16; o >= 1; o >>= 1) mx = fmaxf(mx, __shfl_xor(mx, o, 32));
    float e = (lane < 12) ? expf(myv - mx) : 0.f;
    float se = e;
#pragma unroll
    for (int o = 16; o >= 1; o >>= 1) se += __shfl_xor(se, o, 32);
    const float invs = 1.f / se;

    const float* offp = off + (size_t)m * 192 + h * 24;
    const float refx = ((lq % 60) + 0.5f) * (1.f / 60.f);
    const float refy = ((lq / 60) + 0.5f) * (1.f / 60.f);
    const float* vbase = value + (size_t)b * LIN * D_MODEL + h * 32 + lane;

    const int HW[3] = {60, 30, 15};
    const int ST[3] = {0, 3600, 4500};
    float acc = 0.f;
#pragma unroll
    for (int lev = 0; lev < NLEV; ++lev) {
        const int Hl = HW[lev], Wl = HW[lev], s0 = ST[lev];
        const float fW = (float)Wl, fH = (float)Hl;
#pragma unroll
        for (int p = 0; p < NPNT; ++p) {
            const float ox = offp[lev * 8 + p * 2];
            const float oy = offp[lev * 8 + p * 2 + 1];
            const float px = refx * fW + ox - 0.5f;  // (refx + ox/W)*W - 0.5
            const float py = refy * fH + oy - 0.5f;
            const float x0f = floorf(px), y0f = floorf(py);
            const float fx = px - x0f, fy = py - y0f;
            const int x0 = (int)x0f, y0 = (int)y0f;
            const float aw = __shfl(e, lev * 4 + p, 32) * invs;
            acc += ms_sample(vbase, s0, Wl, Hl, y0,     x0,     (1.f - fx) * (1.f - fy) * aw);
            acc += ms_sample(vbase, s0, Wl, Hl, y0,     x0 + 1, fx * (1.f - fy) * aw);
            acc += ms_sample(vbase, s0, Wl, Hl, y0 + 1, x0,     (1.f - fx) * fy * aw);
            acc += ms_sample(vbase, s0, Wl, Hl, y0 + 1, x0 + 1, fx * fy * aw);
        }
    }
    out[(size_t)m * D_MODEL + h * 32 + lane] = acc;
}

// ---------------------------------------------------------------------------
extern "C" void kernel_launch(void* const* d_in, const int* in_sizes, int n_in,
                              void* d_out, int out_size, void* d_ws, size_t ws_size,
                              hipStream_t stream)
{
    (void)in_sizes; (void)n_in; (void)out_size; (void)ws_size;
    const float* tgt          = (const float*)d_in[0];
    const float* qp           = (const float*)d_in[1];
    const float* src          = (const float*)d_in[2];
    const float* in_proj_w    = (const float*)d_in[5];
    const float* in_proj_b    = (const float*)d_in[6];
    const float* out_proj_w   = (const float*)d_in[7];
    const float* out_proj_b   = (const float*)d_in[8];
    const float* samp_off_w   = (const float*)d_in[9];
    const float* samp_off_b   = (const float*)d_in[10];
    const float* attn_w_w     = (const float*)d_in[11];
    const float* attn_w_b     = (const float*)d_in[12];
    const float* value_proj_w = (const float*)d_in[13];
    const float* value_proj_b = (const float*)d_in[14];
    const float* cross_out_w  = (const float*)d_in[15];
    const float* cross_out_b  = (const float*)d_in[16];
    const float* ln1_g = (const float*)d_in[17];
    const float* ln1_b = (const float*)d_in[18];
    const float* ln2_g = (const float*)d_in[19];
    const float* ln2_b = (const float*)d_in[20];
    const float* ln3_g = (const float*)d_in[21];
    const float* ln3_b = (const float*)d_in[22];
    const float* ffn_w1 = (const float*)d_in[23];
    const float* ffn_b1 = (const float*)d_in[24];
    const float* ffn_w2 = (const float*)d_in[25];
    const float* ffn_b2 = (const float*)d_in[26];
    float* out = (float*)d_out;

    // Workspace arena (floats). SZ = B*LQ*D = 7,372,800.
    const size_t SZ = (size_t)MROWS * D_MODEL;
    float* ws    = (float*)d_ws;
    float* x0    = ws;                       // slot A: 7,372,800
    float* qkv   = ws + SZ;                  // slot B: 22,118,400 (28800x768)
    float* ctx   = ws + SZ + 22118400;       // slot C: 7,372,800
    float* sa    = ctx + SZ;                 // slot D: 7,372,800
    float* t     = sa + SZ;                  // slot E: 7,372,800
    float* qpv   = t + SZ;                   // 1056 floats
    // aliases
    float* value = qkv;                      // 37800*256 = 9,676,800 (in B)
    float* offb  = qkv + 9676800;            // 28800*192 = 5,529,600 (in B)
    float* awb   = qkv + 15206400;           // 28800*96  = 2,764,800 (in B)
    float* msout = x0;                       // slot A reuse
    float* cross = ctx;                      // slot C reuse
    float* t2    = sa;                       // slot D reuse
    float* hidden= x0;                       // slots A+B (29,491,200 = 28800*1024)
    float* ff    = ctx;                      // slot C reuse

    // 0. transpose tgt -> (B,LQ,D)
    transpose_in_kernel<<<7200, 256, 0, stream>>>(tgt, x0);
    // 0b. query_pos projections (extra bias vectors)
    qp_proj_kernel<<<5, 256, 0, stream>>>(qp, in_proj_w, samp_off_w, attn_w_w, qpv);
    // 1. QKV projection (Q,K get query_pos bias; V does not)
    gemm_tn<<<dim3(450, 12), 256, 0, stream>>>(x0, in_proj_w, in_proj_b, qpv, 512,
                                               qkv, MROWS, 768, 256, 0);
    // 2. self-attention (S=8 over batch axis)
    self_attn_kernel<<<3600, 256, 0, stream>>>(qkv, ctx);
    // 3. out_proj
    gemm_tn<<<dim3(450, 4), 256, 0, stream>>>(ctx, out_proj_w, out_proj_b, nullptr, 0,
                                              sa, MROWS, 256, 256, 0);
    // 4. t = LN2(tgt + sa)
    add_ln_kernel<<<7200, 256, 0, stream>>>(x0, sa, ln2_g, ln2_b, t, 0);
    // 5. value projection
    gemm_tn<<<dim3(591, 4), 256, 0, stream>>>(src, value_proj_w, value_proj_b, nullptr, 0,
                                              value, BATCH * LIN, 256, 256, 0);
    // 6. sampling offsets (query = t + query_pos via bias2)
    gemm_tn<<<dim3(450, 3), 256, 0, stream>>>(t, samp_off_w, samp_off_b, qpv + 768, 192,
                                              offb, MROWS, 192, 256, 0);
    // 7. attention weights (raw; softmax inside sampling kernel)
    gemm_tn<<<dim3(450, 2), 256, 0, stream>>>(t, attn_w_w, attn_w_b, qpv + 960, 96,
                                              awb, MROWS, 96, 256, 0);
    // 8. deformable sampling
    msdeform_kernel<<<MROWS, 256, 0, stream>>>(value, offb, awb, msout);
    // 9. cross output projection
    gemm_tn<<<dim3(450, 4), 256, 0, stream>>>(msout, cross_out_w, cross_out_b, nullptr, 0,
                                              cross, MROWS, 256, 256, 0);
    // 10. t2 = LN1(t + cross)
    add_ln_kernel<<<7200, 256, 0, stream>>>(t, cross, ln1_g, ln1_b, t2, 0);
    // 11. FFN layer 1 (+ ReLU)
    gemm_tn<<<dim3(450, 16), 256, 0, stream>>>(t2, ffn_w1, ffn_b1, nullptr, 0,
                                               hidden, MROWS, DFF, 256, 1);
    // 12. FFN layer 2
    gemm_tn<<<dim3(450, 4), 256, 0, stream>>>(hidden, ffn_w2, ffn_b2, nullptr, 0,
                                              ff, MROWS, 256, DFF, 0);
    // 13. out = LN3(t2 + ff), transposed to (LQ,B,D)
    add_ln_kernel<<<7200, 256, 0, stream>>>(t2, ff, ln3_g, ln3_b, out, 1);
}

// Round 2
// 571.317 us; speedup vs baseline: 2.3572x; 2.3572x over previous
//
#include <hip/hip_runtime.h>
#include <hip/hip_bf16.h>
#include <cstddef>
#include <cstdint>

// Problem constants
#define D_MODEL 256
#define NHEAD   8
#define HDIM    32
#define NLEV    3
#define NPNT    4
#define DFF     1024
#define BATCH   8
#define LQ      3600
#define LIN     4725   // 60*60 + 30*30 + 15*15
#define MROWS   (BATCH*LQ)   // 28800; row order is (lq,b): m = lq*8 + b

typedef short bf16x8 __attribute__((ext_vector_type(8)));
typedef float f32x4  __attribute__((ext_vector_type(4)));

__device__ __forceinline__ unsigned short f2b(float x) {
    unsigned int u = __float_as_uint(x);
    unsigned int r = (u + 0x7fffu + ((u >> 16) & 1u)) >> 16;   // RNE
    return (unsigned short)r;
}
__device__ __forceinline__ float b2f(unsigned short s) {
    return __uint_as_float(((unsigned int)s) << 16);
}

#define GLDS16(g, l) __builtin_amdgcn_global_load_lds( \
    (const __attribute__((address_space(1))) void*)(g), \
    (__attribute__((address_space(3))) void*)(l), 16, 0, 0)

// ---------------------------------------------------------------------------
// fp32 -> bf16 bulk convert, 4 elems/thread
__global__ __launch_bounds__(256) void conv_f2b_kernel(
    const float* __restrict__ in, unsigned short* __restrict__ out, int n4)
{
    int i = blockIdx.x * 256 + threadIdx.x;
    if (i >= n4) return;
    float4 v = ((const float4*)in)[i];
    ushort4 o;
    o.x = f2b(v.x); o.y = f2b(v.y); o.z = f2b(v.z); o.w = f2b(v.w);
    ((ushort4*)out)[i] = o;
}

// ---------------------------------------------------------------------------
// Convert all weight matrices into one bf16 arena (concatenated, N x K each).
// Layout (element offsets): w_in 0, w_out 196608, w_val 262144, w_cross 327680,
// w_soaw 393216 (192x256 samp_off then 96x256 attn_w), w_f1 466944, w_f2 729088.
#define WTOT 991232
__global__ __launch_bounds__(256) void wconvert_kernel(
    const float* __restrict__ w_in, const float* __restrict__ w_out,
    const float* __restrict__ w_val, const float* __restrict__ w_cross,
    const float* __restrict__ w_so, const float* __restrict__ w_aw,
    const float* __restrict__ w_f1, const float* __restrict__ w_f2,
    unsigned short* __restrict__ dst)
{
    int idx = (blockIdx.x * 256 + threadIdx.x) * 4;
    if (idx >= WTOT) return;
    const float* src; int off;
    if      (idx < 196608) { src = w_in;    off = idx; }
    else if (idx < 262144) { src = w_out;   off = idx - 196608; }
    else if (idx < 327680) { src = w_val;   off = idx - 262144; }
    else if (idx < 393216) { src = w_cross; off = idx - 327680; }
    else if (idx < 442368) { src = w_so;    off = idx - 393216; }
    else if (idx < 466944) { src = w_aw;    off = idx - 442368; }
    else if (idx < 729088) { src = w_f1;    off = idx - 466944; }
    else                   { src = w_f2;    off = idx - 729088; }
    float4 v = *(const float4*)(src + off);
    ushort4 o;
    o.x = f2b(v.x); o.y = f2b(v.y); o.z = f2b(v.z); o.w = f2b(v.w);
    *(ushort4*)(dst + idx) = o;
}

// ---------------------------------------------------------------------------
// query_pos projections: qpv[0..767] = qp @ in_proj_w^T,
// qpv[768..959] = qp @ samp_off_w^T, qpv[960..1055] = qp @ attn_w_w^T.
// Also cbias[288] = qpv[768+j] + (samp_off_b | attn_w_b)[j] at qpv+1056.
__global__ void qp_proj_kernel(const float* __restrict__ qp,
                               const float* __restrict__ w_in,
                               const float* __restrict__ w_so,
                               const float* __restrict__ w_aw,
                               const float* __restrict__ so_b,
                               const float* __restrict__ aw_b,
                               float* __restrict__ outv)
{
    int o = blockIdx.x * blockDim.x + threadIdx.x;
    if (o >= 768 + 192 + 96) return;
    const float* wrow;
    if (o < 768)       wrow = w_in + (size_t)o * D_MODEL;
    else if (o < 960)  wrow = w_so + (size_t)(o - 768) * D_MODEL;
    else               wrow = w_aw + (size_t)(o - 960) * D_MODEL;
    float acc = 0.f;
    for (int d = 0; d < D_MODEL; ++d) acc += qp[d] * wrow[d];
    outv[o] = acc;
    if (o >= 768) {
        float bias = (o < 960) ? so_b[o - 768] : aw_b[o - 960];
        outv[1056 + (o - 768)] = acc + bias;
    }
}

// ---------------------------------------------------------------------------
// bf16 MFMA GEMM (m97 structure): C[m,n] = act(sum_k A[m,k]*W[n,k] + bias[n]
//   + (n<b2lim ? bias2[n] : 0)).  A: MxK bf16 row-major. W: NxK bf16 (= B^T).
// 128x128 tile, BK=32, 4 waves each 64x64 (4x4 of 16x16x32 MFMA).
// Tail M/N handled by clamped staging rows + guarded stores.
__global__ __launch_bounds__(256) void gemm_bf16(
    const unsigned short* __restrict__ A,
    const unsigned short* __restrict__ W,
    const float* __restrict__ bias,
    const float* __restrict__ bias2, int b2lim,
    float* __restrict__ Cf, unsigned short* __restrict__ Cb,
    int M, int N, int K, int relu)
{
    __shared__ __align__(16) unsigned short As[128 * 32];
    __shared__ __align__(16) unsigned short Bs[128 * 32];
    const int tid  = threadIdx.x;
    const int wave = tid >> 6;
    const int lane = tid & 63;
    const int m0 = blockIdx.x * 128;
    const int n0 = blockIdx.y * 128;

    // staging: wave loads chunks {2w,2w+1} of each tile; chunk = 16 rows x 32 k.
    // lane covers row (lane>>2) of the chunk, bf16 cols (lane&3)*8 .. +7.
    const int lr  = lane >> 2;
    const int lc8 = (lane & 3) * 8;
    int ar0 = m0 + wave * 32 + lr;      if (ar0 > M - 1) ar0 = M - 1;
    int ar1 = m0 + wave * 32 + 16 + lr; if (ar1 > M - 1) ar1 = M - 1;
    int br0 = n0 + wave * 32 + lr;      if (br0 > N - 1) br0 = N - 1;
    int br1 = n0 + wave * 32 + 16 + lr; if (br1 > N - 1) br1 = N - 1;
    const unsigned short* pa0 = A + (size_t)ar0 * K + lc8;
    const unsigned short* pa1 = A + (size_t)ar1 * K + lc8;
    const unsigned short* pb0 = W + (size_t)br0 * K + lc8;
    const unsigned short* pb1 = W + (size_t)br1 * K + lc8;
    unsigned short* la0 = As + wave * 1024;        // chunk 2w   (512 shorts each)
    unsigned short* la1 = As + wave * 1024 + 512;  // chunk 2w+1
    unsigned short* lb0 = Bs + wave * 1024;
    unsigned short* lb1 = Bs + wave * 1024 + 512;

    const int wm = (wave >> 1) * 64;
    const int wn = (wave & 1) * 64;
    const int fr = lane & 15;           // fragment row (m or n)
    const int fk = (lane >> 4) * 8;     // fragment k offset

    f32x4 acc[4][4] = {};

    for (int k0 = 0; k0 < K; k0 += 32) {
        GLDS16(pa0, la0); GLDS16(pa1, la1);
        GLDS16(pb0, lb0); GLDS16(pb1, lb1);
        pa0 += 32; pa1 += 32; pb0 += 32; pb1 += 32;
        __syncthreads();
        bf16x8 af[4], bfv[4];
#pragma unroll
        for (int i = 0; i < 4; ++i)
            af[i] = *(const bf16x8*)&As[(wm + i * 16 + fr) * 32 + fk];
#pragma unroll
        for (int j = 0; j < 4; ++j)
            bfv[j] = *(const bf16x8*)&Bs[(wn + j * 16 + fr) * 32 + fk];
#pragma unroll
        for (int i = 0; i < 4; ++i)
#pragma unroll
            for (int j = 0; j < 4; ++j)
                acc[i][j] = __builtin_amdgcn_mfma_f32_16x16x32_bf16(
                    af[i], bfv[j], acc[i][j], 0, 0, 0);
        __syncthreads();
    }

    // C/D layout: col = lane&15, row = (lane>>4)*4 + reg
    const int quad = lane >> 4;
#pragma unroll
    for (int j = 0; j < 4; ++j) {
        const int col = n0 + wn + j * 16 + fr;
        if (col >= N) continue;
        float bv = 0.f;
        if (bias) bv += bias[col];
        if (bias2 && col < b2lim) bv += bias2[col];
#pragma unroll
        for (int i = 0; i < 4; ++i) {
#pragma unroll
            for (int r = 0; r < 4; ++r) {
                const int row = m0 + wm + i * 16 + quad * 4 + r;
                if (row >= M) continue;
                float v = acc[i][j][r] + bv;
                if (relu) v = fmaxf(v, 0.f);
                if (Cf) Cf[(size_t)row * N + col] = v;
                if (Cb) Cb[(size_t)row * N + col] = f2b(v);
            }
        }
    }
}

// ---------------------------------------------------------------------------
// Self-attention over S=8 (batch axis). Row order (lq,b): row = n*8 + s.
// qkv bf16 [row][768] (q 0-255, k 256-511, v 512-767); ctx out bf16 [row][256].
__global__ __launch_bounds__(256) void self_attn_kernel(
    const unsigned short* __restrict__ qkv, unsigned short* __restrict__ ctx)
{
    __shared__ float sh[8][768];
    __shared__ float ls[8][8][8];   // [h][s][t]
    const int n = blockIdx.x;
    const int t = threadIdx.x;
#pragma unroll
    for (int s = 0; s < 8; ++s) {
        const unsigned short* row = qkv + (size_t)(n * 8 + s) * 768;
        sh[s][t]       = b2f(row[t]);
        sh[s][t + 256] = b2f(row[t + 256]);
        sh[s][t + 512] = b2f(row[t + 512]);
    }
    __syncthreads();
    const int h = t >> 5, j = t & 31;
#pragma unroll
    for (int pair = j; pair < 64; pair += 32) {
        const int s = pair >> 3, tt = pair & 7;
        float acc = 0.f;
#pragma unroll
        for (int d = 0; d < 32; ++d)
            acc += sh[s][h * 32 + d] * sh[tt][256 + h * 32 + d];
        ls[h][s][tt] = acc * 0.17677669529663687f;  // 1/sqrt(32)
    }
    __syncthreads();
    if (t < 64) {
        const int hh = t >> 3, s = t & 7;
        float mx = -1e30f;
        for (int tt = 0; tt < 8; ++tt) mx = fmaxf(mx, ls[hh][s][tt]);
        float sum = 0.f;
        for (int tt = 0; tt < 8; ++tt) { float e = expf(ls[hh][s][tt] - mx); ls[hh][s][tt] = e; sum += e; }
        const float inv = 1.f / sum;
        for (int tt = 0; tt < 8; ++tt) ls[hh][s][tt] *= inv;
    }
    __syncthreads();
#pragma unroll
    for (int s = 0; s < 8; ++s) {
        float acc = 0.f;
#pragma unroll
        for (int tt = 0; tt < 8; ++tt)
            acc += ls[h][s][tt] * sh[tt][512 + h * 32 + j];
        ctx[(size_t)(n * 8 + s) * D_MODEL + h * 32 + j] = f2b(acc);
    }
}

// ---------------------------------------------------------------------------
// outf[m] = LN(x[m] + y[m]) * g + b, optional bf16 copy. One wave per row.
__global__ __launch_bounds__(256) void add_ln_kernel(
    const float* __restrict__ x, const float* __restrict__ y,
    const float* __restrict__ g, const float* __restrict__ bb,
    float* __restrict__ outf, unsigned short* __restrict__ outb)
{
    const int w = threadIdx.x >> 6, lane = threadIdx.x & 63;
    const int m = blockIdx.x * 4 + w;
    const float4 xv = ((const float4*)(x + (size_t)m * D_MODEL))[lane];
    const float4 yv = ((const float4*)(y + (size_t)m * D_MODEL))[lane];
    const float v0 = xv.x + yv.x, v1 = xv.y + yv.y, v2 = xv.z + yv.z, v3 = xv.w + yv.w;
    float s1 = v0 + v1 + v2 + v3;
    float s2 = v0 * v0 + v1 * v1 + v2 * v2 + v3 * v3;
#pragma unroll
    for (int o = 1; o < 64; o <<= 1) {
        s1 += __shfl_xor(s1, o);
        s2 += __shfl_xor(s2, o);
    }
    const float mean = s1 * (1.f / 256.f);
    const float var  = s2 * (1.f / 256.f) - mean * mean;
    const float inv  = rsqrtf(var + 1e-5f);
    const float4 gv = ((const float4*)g)[lane];
    const float4 bv = ((const float4*)bb)[lane];
    float4 o4;
    o4.x = (v0 - mean) * inv * gv.x + bv.x;
    o4.y = (v1 - mean) * inv * gv.y + bv.y;
    o4.z = (v2 - mean) * inv * gv.z + bv.z;
    o4.w = (v3 - mean) * inv * gv.w + bv.w;
    ((float4*)outf)[(size_t)m * 64 + lane] = o4;
    if (outb) {
        ushort4 ob;
        ob.x = f2b(o4.x); ob.y = f2b(o4.y); ob.z = f2b(o4.z); ob.w = f2b(o4.w);
        ((ushort4*)outb)[(size_t)m * 64 + lane] = ob;
    }
}

// ---------------------------------------------------------------------------
// Deformable sampling. m = blockIdx.x (row, (lq,b) order): b = m&7, lq = m>>3.
// comb [m][288]: cols 0-191 offsets, 192-287 raw attn weights. value bf16.
__device__ __forceinline__ float ms_sample(const unsigned short* vbase, int s0,
                                           int Wl, int Hl, int yi, int xi, float w)
{
    const bool valid = (xi >= 0) & (xi < Wl) & (yi >= 0) & (yi < Hl);
    const int xc = min(max(xi, 0), Wl - 1);
    const int yc = min(max(yi, 0), Hl - 1);
    const float v = b2f(vbase[(size_t)(s0 + yc * Wl + xc) * D_MODEL]);
    return valid ? v * w : 0.f;
}

__global__ __launch_bounds__(256) void msdeform_kernel(
    const unsigned short* __restrict__ value,   // [b*LIN + lin][256] bf16
    const float* __restrict__ comb,             // [m][288]
    unsigned short* __restrict__ out)           // [m][256] bf16
{
    const int m  = blockIdx.x;
    const int b  = m & 7;
    const int lq = m >> 3;
    const int h    = threadIdx.x >> 5;
    const int lane = threadIdx.x & 31;

    const float* awp = comb + (size_t)m * 288 + 192 + h * 12;
    float myv = (lane < 12) ? awp[lane] : -1e30f;
    float mx = myv;
#pragma unroll
    for (int o = 16; o >= 1; o >>= 1) mx = fmaxf(mx, __shfl_xor(mx, o, 32));
    float e = (lane < 12) ? expf(myv - mx) : 0.f;
    float se = e;
#pragma unroll
    for (int o = 16; o >= 1; o >>= 1) se += __shfl_xor(se, o, 32);
    const float invs = 1.f / se;

    const float* offp = comb + (size_t)m * 288 + h * 24;
    const float refx = ((lq % 60) + 0.5f) * (1.f / 60.f);
    const float refy = ((lq / 60) + 0.5f) * (1.f / 60.f);
    const unsigned short* vbase = value + (size_t)b * LIN * D_MODEL + h * 32 + lane;

    const int HW[3] = {60, 30, 15};
    const int ST[3] = {0, 3600, 4500};
    float acc = 0.f;
#pragma unroll
    for (int lev = 0; lev < NLEV; ++lev) {
        const int Hl = HW[lev], Wl = HW[lev], s0 = ST[lev];
        const float fW = (float)Wl, fH = (float)Hl;
#pragma unroll
        for (int p = 0; p < NPNT; ++p) {
            const float ox = offp[lev * 8 + p * 2];
            const float oy = offp[lev * 8 + p * 2 + 1];
            const float px = refx * fW + ox - 0.5f;
            const float py = refy * fH + oy - 0.5f;
            const float x0f = floorf(px), y0f = floorf(py);
            const float fx = px - x0f, fy = py - y0f;
            const int x0 = (int)x0f, y0 = (int)y0f;
            const float aw = __shfl(e, lev * 4 + p, 32) * invs;
            acc += ms_sample(vbase, s0, Wl, Hl, y0,     x0,     (1.f - fx) * (1.f - fy) * aw);
            acc += ms_sample(vbase, s0, Wl, Hl, y0,     x0 + 1, fx * (1.f - fy) * aw);
            acc += ms_sample(vbase, s0, Wl, Hl, y0 + 1, x0,     (1.f - fx) * fy * aw);
            acc += ms_sample(vbase, s0, Wl, Hl, y0 + 1, x0 + 1, fx * fy * aw);
        }
    }
    out[(size_t)m * D_MODEL + h * 32 + lane] = f2b(acc);
}

// ---------------------------------------------------------------------------
extern "C" void kernel_launch(void* const* d_in, const int* in_sizes, int n_in,
                              void* d_out, int out_size, void* d_ws, size_t ws_size,
                              hipStream_t stream)
{
    (void)in_sizes; (void)n_in; (void)out_size; (void)ws_size;
    const float* tgt          = (const float*)d_in[0];   // (LQ,B,D) = (lq,b)-major rows
    const float* qp           = (const float*)d_in[1];
    const float* src          = (const float*)d_in[2];
    const float* in_proj_w    = (const float*)d_in[5];
    const float* in_proj_b    = (const float*)d_in[6];
    const float* out_proj_w   = (const float*)d_in[7];
    const float* out_proj_b   = (const float*)d_in[8];
    const float* samp_off_w   = (const float*)d_in[9];
    const float* samp_off_b   = (const float*)d_in[10];
    const float* attn_w_w     = (const float*)d_in[11];
    const float* attn_w_b     = (const float*)d_in[12];
    const float* value_proj_w = (const float*)d_in[13];
    const float* value_proj_b = (const float*)d_in[14];
    const float* cross_out_w  = (const float*)d_in[15];
    const float* cross_out_b  = (const float*)d_in[16];
    const float* ln1_g = (const float*)d_in[17];
    const float* ln1_b = (const float*)d_in[18];
    const float* ln2_g = (const float*)d_in[19];
    const float* ln2_b = (const float*)d_in[20];
    const float* ln3_g = (const float*)d_in[21];
    const float* ln3_b = (const float*)d_in[22];
    const float* ffn_w1 = (const float*)d_in[23];
    const float* ffn_b1 = (const float*)d_in[24];
    const float* ffn_w2 = (const float*)d_in[25];
    const float* ffn_b2 = (const float*)d_in[26];
    float* out = (float*)d_out;

    // ---- fp32 arena (floats). Lifetime-aliased; total 92,165,376 B. ----
    float* ws    = (float*)d_ws;
    float* t     = ws;                    // LN2 out (residual); later ff
    float* ff    = ws;
    float* sa    = ws + 7372800;          // self-attn proj; later t2
    float* t2    = sa;
    float* comb  = ws + 14745600;         // 28800x288 off+aw; later cross
    float* cross = comb;
    float* qpv   = ws + 23040000;         // 1056 qp-proj + 288 cbias
    float* cbias = qpv + 1056;

    // ---- bf16 arena (ushort), after fp32 arena ----
    unsigned short* bws    = (unsigned short*)((char*)d_ws + 92165376);
    unsigned short* s1     = bws;                  // tgtb -> ctxb -> tb -> t2b
    unsigned short* tgtb   = s1;
    unsigned short* ctxb   = s1;
    unsigned short* tb     = s1;
    unsigned short* t2b    = s1;
    unsigned short* s2     = bws + 7372800;        // qkvb / valueb+msoutb / hiddenb
    unsigned short* qkvb   = s2;
    unsigned short* valueb = s2;
    unsigned short* msoutb = s2 + 9676800;
    unsigned short* hiddenb= s2;
    unsigned short* srcb   = bws + 36864000;
    unsigned short* wtsb   = bws + 46540800;       // 991,232 shorts

    // 1. conversions
    conv_f2b_kernel<<<7200, 256, 0, stream>>>(tgt, tgtb, 1843200);
    conv_f2b_kernel<<<9450, 256, 0, stream>>>(src, srcb, 2419200);
    qp_proj_kernel<<<5, 256, 0, stream>>>(qp, in_proj_w, samp_off_w, attn_w_w,
                                          samp_off_b, attn_w_b, qpv);
    wconvert_kernel<<<968, 256, 0, stream>>>(in_proj_w, out_proj_w, value_proj_w,
                                             cross_out_w, samp_off_w, attn_w_w,
                                             ffn_w1, ffn_w2, wtsb);
    // 2. QKV projection (Q,K rows get query_pos bias via qpv, cols < 512)
    gemm_bf16<<<dim3(225, 6), 256, 0, stream>>>(tgtb, wtsb + 0, in_proj_b, qpv, 512,
                                                nullptr, qkvb, MROWS, 768, 256, 0);
    // 3. self-attention over batch axis
    self_attn_kernel<<<3600, 256, 0, stream>>>(qkvb, ctxb);
    // 4. out_proj
    gemm_bf16<<<dim3(225, 2), 256, 0, stream>>>(ctxb, wtsb + 196608, out_proj_b, nullptr, 0,
                                                sa, nullptr, MROWS, 256, 256, 0);
    // 5. t = LN2(tgt + sa)  (tgt rows are natively (lq,b)-major)
    add_ln_kernel<<<7200, 256, 0, stream>>>(tgt, sa, ln2_g, ln2_b, t, tb);
    // 6. value projection (M = 37800, tail tile handled)
    gemm_bf16<<<dim3(296, 2), 256, 0, stream>>>(srcb, wtsb + 262144, value_proj_b, nullptr, 0,
                                                nullptr, valueb, BATCH * LIN, 256, 256, 0);
    // 7. fused sampling-offset + attn-weight projection (N = 288)
    gemm_bf16<<<dim3(225, 3), 256, 0, stream>>>(tb, wtsb + 393216, cbias, nullptr, 0,
                                                comb, nullptr, MROWS, 288, 256, 0);
    // 8. deformable sampling
    msdeform_kernel<<<MROWS, 256, 0, stream>>>(valueb, comb, msoutb);
    // 9. cross output projection
    gemm_bf16<<<dim3(225, 2), 256, 0, stream>>>(msoutb, wtsb + 327680, cross_out_b, nullptr, 0,
                                                cross, nullptr, MROWS, 256, 256, 0);
    // 10. t2 = LN1(t + cross)
    add_ln_kernel<<<7200, 256, 0, stream>>>(t, cross, ln1_g, ln1_b, t2, t2b);
    // 11. FFN layer 1 (+ReLU), bf16 out
    gemm_bf16<<<dim3(225, 8), 256, 0, stream>>>(t2b, wtsb + 466944, ffn_b1, nullptr, 0,
                                                nullptr, hiddenb, MROWS, DFF, 256, 1);
    // 12. FFN layer 2
    gemm_bf16<<<dim3(225, 2), 256, 0, stream>>>(hiddenb, wtsb + 729088, ffn_b2, nullptr, 0,
                                                ff, nullptr, MROWS, 256, DFF, 0);
    // 13. out = LN3(t2 + ff)  (output order is natively (lq,b)-major)
    add_ln_kernel<<<7200, 256, 0, stream>>>(t2, ff, ln3_g, ln3_b, out, nullptr);
}

// Round 3
// 523.212 us; speedup vs baseline: 2.5740x; 1.0919x over previous
//
#include <hip/hip_runtime.h>
#include <hip/hip_bf16.h>
#include <cstddef>
#include <cstdint>

// Problem constants
#define D_MODEL 256
#define NHEAD   8
#define HDIM    32
#define NLEV    3
#define NPNT    4
#define DFF     1024
#define BATCH   8
#define LQ      3600
#define LIN     4725   // 60*60 + 30*30 + 15*15
#define MROWS   (BATCH*LQ)   // 28800; row order is (lq,b): m = lq*8 + b

typedef short bf16x8 __attribute__((ext_vector_type(8)));
typedef float f32x4  __attribute__((ext_vector_type(4)));

__device__ __forceinline__ unsigned short f2b(float x) {
    unsigned int u = __float_as_uint(x);
    unsigned int r = (u + 0x7fffu + ((u >> 16) & 1u)) >> 16;   // RNE
    return (unsigned short)r;
}
__device__ __forceinline__ float b2f(unsigned short s) {
    return __uint_as_float(((unsigned int)s) << 16);
}

#define GLDS16(g, l) __builtin_amdgcn_global_load_lds( \
    (const __attribute__((address_space(1))) void*)(g), \
    (__attribute__((address_space(3))) void*)(l), 16, 0, 0)

// ---------------------------------------------------------------------------
// fp32 -> bf16 bulk convert, 4 elems/thread
__global__ __launch_bounds__(256) void conv_f2b_kernel(
    const float* __restrict__ in, unsigned short* __restrict__ out, int n4)
{
    int i = blockIdx.x * 256 + threadIdx.x;
    if (i >= n4) return;
    float4 v = ((const float4*)in)[i];
    ushort4 o;
    o.x = f2b(v.x); o.y = f2b(v.y); o.z = f2b(v.z); o.w = f2b(v.w);
    ((ushort4*)out)[i] = o;
}

// ---------------------------------------------------------------------------
// Convert all weight matrices into one bf16 arena (concatenated, N x K each).
#define WTOT 991232
__global__ __launch_bounds__(256) void wconvert_kernel(
    const float* __restrict__ w_in, const float* __restrict__ w_out,
    const float* __restrict__ w_val, const float* __restrict__ w_cross,
    const float* __restrict__ w_so, const float* __restrict__ w_aw,
    const float* __restrict__ w_f1, const float* __restrict__ w_f2,
    unsigned short* __restrict__ dst)
{
    int idx = (blockIdx.x * 256 + threadIdx.x) * 4;
    if (idx >= WTOT) return;
    const float* src; int off;
    if      (idx < 196608) { src = w_in;    off = idx; }
    else if (idx < 262144) { src = w_out;   off = idx - 196608; }
    else if (idx < 327680) { src = w_val;   off = idx - 262144; }
    else if (idx < 393216) { src = w_cross; off = idx - 327680; }
    else if (idx < 442368) { src = w_so;    off = idx - 393216; }
    else if (idx < 466944) { src = w_aw;    off = idx - 442368; }
    else if (idx < 729088) { src = w_f1;    off = idx - 466944; }
    else                   { src = w_f2;    off = idx - 729088; }
    float4 v = *(const float4*)(src + off);
    ushort4 o;
    o.x = f2b(v.x); o.y = f2b(v.y); o.z = f2b(v.z); o.w = f2b(v.w);
    *(ushort4*)(dst + idx) = o;
}

// ---------------------------------------------------------------------------
// query_pos projections + combined samp_off/attn_w bias
__global__ void qp_proj_kernel(const float* __restrict__ qp,
                               const float* __restrict__ w_in,
                               const float* __restrict__ w_so,
                               const float* __restrict__ w_aw,
                               const float* __restrict__ so_b,
                               const float* __restrict__ aw_b,
                               float* __restrict__ outv)
{
    int o = blockIdx.x * blockDim.x + threadIdx.x;
    if (o >= 768 + 192 + 96) return;
    const float* wrow;
    if (o < 768)       wrow = w_in + (size_t)o * D_MODEL;
    else if (o < 960)  wrow = w_so + (size_t)(o - 768) * D_MODEL;
    else               wrow = w_aw + (size_t)(o - 960) * D_MODEL;
    float acc = 0.f;
    for (int d = 0; d < D_MODEL; ++d) acc += qp[d] * wrow[d];
    outv[o] = acc;
    if (o >= 768) {
        float bias = (o < 960) ? so_b[o - 768] : aw_b[o - 960];
        outv[1056 + (o - 768)] = acc + bias;
    }
}

// ---------------------------------------------------------------------------
// bf16 MFMA GEMM (m97 structure), 128x128 tile, BK=32.
__global__ __launch_bounds__(256) void gemm_bf16(
    const unsigned short* __restrict__ A,
    const unsigned short* __restrict__ W,
    const float* __restrict__ bias,
    const float* __restrict__ bias2, int b2lim,
    float* __restrict__ Cf, unsigned short* __restrict__ Cb,
    int M, int N, int K, int relu)
{
    __shared__ __align__(16) unsigned short As[128 * 32];
    __shared__ __align__(16) unsigned short Bs[128 * 32];
    const int tid  = threadIdx.x;
    const int wave = tid >> 6;
    const int lane = tid & 63;
    const int m0 = blockIdx.x * 128;
    const int n0 = blockIdx.y * 128;

    const int lr  = lane >> 2;
    const int lc8 = (lane & 3) * 8;
    int ar0 = m0 + wave * 32 + lr;      if (ar0 > M - 1) ar0 = M - 1;
    int ar1 = m0 + wave * 32 + 16 + lr; if (ar1 > M - 1) ar1 = M - 1;
    int br0 = n0 + wave * 32 + lr;      if (br0 > N - 1) br0 = N - 1;
    int br1 = n0 + wave * 32 + 16 + lr; if (br1 > N - 1) br1 = N - 1;
    const unsigned short* pa0 = A + (size_t)ar0 * K + lc8;
    const unsigned short* pa1 = A + (size_t)ar1 * K + lc8;
    const unsigned short* pb0 = W + (size_t)br0 * K + lc8;
    const unsigned short* pb1 = W + (size_t)br1 * K + lc8;
    unsigned short* la0 = As + wave * 1024;
    unsigned short* la1 = As + wave * 1024 + 512;
    unsigned short* lb0 = Bs + wave * 1024;
    unsigned short* lb1 = Bs + wave * 1024 + 512;

    const int wm = (wave >> 1) * 64;
    const int wn = (wave & 1) * 64;
    const int fr = lane & 15;
    const int fk = (lane >> 4) * 8;

    f32x4 acc[4][4] = {};

    for (int k0 = 0; k0 < K; k0 += 32) {
        GLDS16(pa0, la0); GLDS16(pa1, la1);
        GLDS16(pb0, lb0); GLDS16(pb1, lb1);
        pa0 += 32; pa1 += 32; pb0 += 32; pb1 += 32;
        __syncthreads();
        bf16x8 af[4], bfv[4];
#pragma unroll
        for (int i = 0; i < 4; ++i)
            af[i] = *(const bf16x8*)&As[(wm + i * 16 + fr) * 32 + fk];
#pragma unroll
        for (int j = 0; j < 4; ++j)
            bfv[j] = *(const bf16x8*)&Bs[(wn + j * 16 + fr) * 32 + fk];
#pragma unroll
        for (int i = 0; i < 4; ++i)
#pragma unroll
            for (int j = 0; j < 4; ++j)
                acc[i][j] = __builtin_amdgcn_mfma_f32_16x16x32_bf16(
                    af[i], bfv[j], acc[i][j], 0, 0, 0);
        __syncthreads();
    }

    const int quad = lane >> 4;
#pragma unroll
    for (int j = 0; j < 4; ++j) {
        const int col = n0 + wn + j * 16 + fr;
        if (col >= N) continue;
        float bv = 0.f;
        if (bias) bv += bias[col];
        if (bias2 && col < b2lim) bv += bias2[col];
#pragma unroll
        for (int i = 0; i < 4; ++i) {
#pragma unroll
            for (int r = 0; r < 4; ++r) {
                const int row = m0 + wm + i * 16 + quad * 4 + r;
                if (row >= M) continue;
                float v = acc[i][j][r] + bv;
                if (relu) v = fmaxf(v, 0.f);
                if (Cf) Cf[(size_t)row * N + col] = v;
                if (Cb) Cb[(size_t)row * N + col] = f2b(v);
            }
        }
    }
}

// ---------------------------------------------------------------------------
// Self-attention over S=8 (batch axis). Row order (lq,b): row = n*8 + s.
__global__ __launch_bounds__(256) void self_attn_kernel(
    const unsigned short* __restrict__ qkv, unsigned short* __restrict__ ctx)
{
    __shared__ float sh[8][768];
    __shared__ float ls[8][8][8];   // [h][s][t]
    const int n = blockIdx.x;
    const int t = threadIdx.x;
#pragma unroll
    for (int s = 0; s < 8; ++s) {
        const unsigned short* row = qkv + (size_t)(n * 8 + s) * 768;
        sh[s][t]       = b2f(row[t]);
        sh[s][t + 256] = b2f(row[t + 256]);
        sh[s][t + 512] = b2f(row[t + 512]);
    }
    __syncthreads();
    const int h = t >> 5, j = t & 31;
#pragma unroll
    for (int pair = j; pair < 64; pair += 32) {
        const int s = pair >> 3, tt = pair & 7;
        float acc = 0.f;
#pragma unroll
        for (int d = 0; d < 32; ++d)
            acc += sh[s][h * 32 + d] * sh[tt][256 + h * 32 + d];
        ls[h][s][tt] = acc * 0.17677669529663687f;
    }
    __syncthreads();
    if (t < 64) {
        const int hh = t >> 3, s = t & 7;
        float mx = -1e30f;
        for (int tt = 0; tt < 8; ++tt) mx = fmaxf(mx, ls[hh][s][tt]);
        float sum = 0.f;
        for (int tt = 0; tt < 8; ++tt) { float e = expf(ls[hh][s][tt] - mx); ls[hh][s][tt] = e; sum += e; }
        const float inv = 1.f / sum;
        for (int tt = 0; tt < 8; ++tt) ls[hh][s][tt] *= inv;
    }
    __syncthreads();
#pragma unroll
    for (int s = 0; s < 8; ++s) {
        float acc = 0.f;
#pragma unroll
        for (int tt = 0; tt < 8; ++tt)
            acc += ls[h][s][tt] * sh[tt][512 + h * 32 + j];
        ctx[(size_t)(n * 8 + s) * D_MODEL + h * 32 + j] = f2b(acc);
    }
}

// ---------------------------------------------------------------------------
// outf[m] = LN(x[m] + y[m]) * g + b, optional bf16 copy. One wave per row.
__global__ __launch_bounds__(256) void add_ln_kernel(
    const float* __restrict__ x, const float* __restrict__ y,
    const float* __restrict__ g, const float* __restrict__ bb,
    float* __restrict__ outf, unsigned short* __restrict__ outb)
{
    const int w = threadIdx.x >> 6, lane = threadIdx.x & 63;
    const int m = blockIdx.x * 4 + w;
    const float4 xv = ((const float4*)(x + (size_t)m * D_MODEL))[lane];
    const float4 yv = ((const float4*)(y + (size_t)m * D_MODEL))[lane];
    const float v0 = xv.x + yv.x, v1 = xv.y + yv.y, v2 = xv.z + yv.z, v3 = xv.w + yv.w;
    float s1 = v0 + v1 + v2 + v3;
    float s2 = v0 * v0 + v1 * v1 + v2 * v2 + v3 * v3;
#pragma unroll
    for (int o = 1; o < 64; o <<= 1) {
        s1 += __shfl_xor(s1, o);
        s2 += __shfl_xor(s2, o);
    }
    const float mean = s1 * (1.f / 256.f);
    const float var  = s2 * (1.f / 256.f) - mean * mean;
    const float inv  = rsqrtf(var + 1e-5f);
    const float4 gv = ((const float4*)g)[lane];
    const float4 bv = ((const float4*)bb)[lane];
    float4 o4;
    o4.x = (v0 - mean) * inv * gv.x + bv.x;
    o4.y = (v1 - mean) * inv * gv.y + bv.y;
    o4.z = (v2 - mean) * inv * gv.z + bv.z;
    o4.w = (v3 - mean) * inv * gv.w + bv.w;
    ((float4*)outf)[(size_t)m * 64 + lane] = o4;
    if (outb) {
        ushort4 ob;
        ob.x = f2b(o4.x); ob.y = f2b(o4.y); ob.z = f2b(o4.z); ob.w = f2b(o4.w);
        ((ushort4*)outb)[(size_t)m * 64 + lane] = ob;
    }
}

// ---------------------------------------------------------------------------
// msprep: one thread per (m,h). Reads comb row (offsets+raw aw), computes
// softmax + bilinear coords + validity-folded weights ONCE, packs 12 B/point,
// writes IN PLACE over the same comb row (whole rows per block; barrier
// between read and write). Output per (m,h) at byte m*1152 + h*144:
//   12 x { u32 pack = idx | sx<<16 | syW<<17 ; u32 w00|w01(bf16) ; u32 w10|w11 }
__global__ __launch_bounds__(256) void msprep_kernel(float* __restrict__ comb)
{
    const int tid = threadIdx.x;
    const int m = blockIdx.x * 32 + (tid >> 3);
    const int h = tid & 7;
    const int lq = m >> 3;
    const float* offp = comb + (size_t)m * 288 + h * 24;
    const float* awp  = comb + (size_t)m * 288 + 192 + h * 12;
    float off[24], aw[12];
#pragma unroll
    for (int i = 0; i < 6; ++i) *(float4*)&off[i * 4] = ((const float4*)offp)[i];
#pragma unroll
    for (int i = 0; i < 3; ++i) *(float4*)&aw[i * 4] = ((const float4*)awp)[i];

    float mx = aw[0];
#pragma unroll
    for (int i = 1; i < 12; ++i) mx = fmaxf(mx, aw[i]);
    float se = 0.f;
#pragma unroll
    for (int i = 0; i < 12; ++i) { aw[i] = __expf(aw[i] - mx); se += aw[i]; }
    const float inv = 1.f / se;

    const float refx = ((lq % 60) + 0.5f) * (1.f / 60.f);
    const float refy = ((lq / 60) + 0.5f) * (1.f / 60.f);
    const int HW[3] = {60, 30, 15};
    const int ST[3] = {0, 3600, 4500};

    unsigned int outv[36];
#pragma unroll
    for (int lev = 0; lev < NLEV; ++lev) {
        const int Wl = HW[lev], Hl = HW[lev], s0 = ST[lev];
        const float fWl = (float)Wl, fHl = (float)Hl;
#pragma unroll
        for (int p = 0; p < NPNT; ++p) {
            const int pt = lev * 4 + p;
            const float ox = off[lev * 8 + p * 2];
            const float oy = off[lev * 8 + p * 2 + 1];
            const float px = refx * fWl + ox - 0.5f;
            const float py = refy * fHl + oy - 0.5f;
            const float x0f = floorf(px), y0f = floorf(py);
            const float fx = px - x0f, fy = py - y0f;
            const int x0 = (int)x0f, y0 = (int)y0f;
            const float aww = aw[pt] * inv;
            const float vx0 = (x0 >= 0 && x0 < Wl) ? 1.f : 0.f;
            const float vx1 = (x0 >= -1 && x0 < Wl - 1) ? 1.f : 0.f;
            const float vy0 = (y0 >= 0 && y0 < Hl) ? 1.f : 0.f;
            const float vy1 = (y0 >= -1 && y0 < Hl - 1) ? 1.f : 0.f;
            const int xc0 = min(max(x0, 0), Wl - 1);
            const int xc1 = min(max(x0 + 1, 0), Wl - 1);
            const int yc0 = min(max(y0, 0), Hl - 1);
            const int yc1 = min(max(y0 + 1, 0), Hl - 1);
            const unsigned int sx  = (unsigned int)(xc1 - xc0);
            const unsigned int syW = (unsigned int)((yc1 - yc0) * Wl);
            const unsigned int idx = (unsigned int)(s0 + yc0 * Wl + xc0);
            const float w00 = (1.f - fx) * (1.f - fy) * aww * vx0 * vy0;
            const float w01 = fx * (1.f - fy) * aww * vx1 * vy0;
            const float w10 = (1.f - fx) * fy * aww * vx0 * vy1;
            const float w11 = fx * fy * aww * vx1 * vy1;
            outv[pt * 3]     = idx | (sx << 16) | (syW << 17);
            outv[pt * 3 + 1] = (unsigned int)f2b(w00) | ((unsigned int)f2b(w01) << 16);
            outv[pt * 3 + 2] = (unsigned int)f2b(w10) | ((unsigned int)f2b(w11) << 16);
        }
    }
    __syncthreads();
    uint4* dst = (uint4*)((char*)comb + (size_t)m * 1152 + h * 144);
#pragma unroll
    for (int i = 0; i < 9; ++i) dst[i] = *(uint4*)&outv[i * 4];
}

// ---------------------------------------------------------------------------
// Hot deformable sampling. Block = 4 rows of the SAME batch (b = bid&7 keeps
// round-robin XCD -> batch locality; per-XCD value slice = 2.4 MB < 4 MB L2).
// 64 lanes/row, 4 channels/lane, ushort4 gathers.
__global__ __launch_bounds__(256) void msdeform_kernel(
    const unsigned short* __restrict__ value,   // [b*LIN + pix][256] bf16
    const unsigned int* __restrict__ meta,      // packed by msprep
    unsigned short* __restrict__ out)           // [m][256] bf16
{
    const int bid = blockIdx.x;
    const int b   = bid & 7;
    const int lq0 = (bid >> 3) * 4;
    const int r    = threadIdx.x >> 6;
    const int lane = threadIdx.x & 63;
    const int h = lane >> 3;
    const int l = lane & 7;
    const int m = (lq0 + r) * 8 + b;

    const unsigned int* mp = meta + (size_t)m * 288 + h * 36;
    uint4 md[9];
#pragma unroll
    for (int i = 0; i < 9; ++i) md[i] = ((const uint4*)mp)[i];
    const unsigned int* mw = (const unsigned int*)md;

    const unsigned short* vbase = value + (size_t)b * LIN * 256 + h * 32 + l * 4;

    float a0 = 0.f, a1 = 0.f, a2 = 0.f, a3 = 0.f;
#pragma unroll
    for (int p = 0; p < 12; ++p) {
        const unsigned int pack = mw[p * 3];
        const unsigned int wlo  = mw[p * 3 + 1];
        const unsigned int whi  = mw[p * 3 + 2];
        const unsigned int i00 = pack & 0xFFFFu;
        const unsigned int sx  = (pack >> 16) & 1u;
        const unsigned int syW = pack >> 17;
        const unsigned int i01 = i00 + sx;
        const unsigned int i10 = i00 + syW;
        const unsigned int i11 = i10 + sx;
        const float w00 = __uint_as_float(wlo << 16);
        const float w01 = __uint_as_float(wlo & 0xFFFF0000u);
        const float w10 = __uint_as_float(whi << 16);
        const float w11 = __uint_as_float(whi & 0xFFFF0000u);
        const ushort4 g00 = *(const ushort4*)(vbase + (size_t)i00 * 256);
        const ushort4 g01 = *(const ushort4*)(vbase + (size_t)i01 * 256);
        const ushort4 g10 = *(const ushort4*)(vbase + (size_t)i10 * 256);
        const ushort4 g11 = *(const ushort4*)(vbase + (size_t)i11 * 256);
        a0 += b2f(g00.x) * w00 + b2f(g01.x) * w01 + b2f(g10.x) * w10 + b2f(g11.x) * w11;
        a1 += b2f(g00.y) * w00 + b2f(g01.y) * w01 + b2f(g10.y) * w10 + b2f(g11.y) * w11;
        a2 += b2f(g00.z) * w00 + b2f(g01.z) * w01 + b2f(g10.z) * w10 + b2f(g11.z) * w11;
        a3 += b2f(g00.w) * w00 + b2f(g01.w) * w01 + b2f(g10.w) * w10 + b2f(g11.w) * w11;
    }
    ushort4 o;
    o.x = f2b(a0); o.y = f2b(a1); o.z = f2b(a2); o.w = f2b(a3);
    *(ushort4*)(out + (size_t)m * 256 + h * 32 + l * 4) = o;
}

// ---------------------------------------------------------------------------
extern "C" void kernel_launch(void* const* d_in, const int* in_sizes, int n_in,
                              void* d_out, int out_size, void* d_ws, size_t ws_size,
                              hipStream_t stream)
{
    (void)in_sizes; (void)n_in; (void)out_size; (void)ws_size;
    const float* tgt          = (const float*)d_in[0];   // (LQ,B,D) = (lq,b)-major rows
    const float* qp           = (const float*)d_in[1];
    const float* src          = (const float*)d_in[2];
    const float* in_proj_w    = (const float*)d_in[5];
    const float* in_proj_b    = (const float*)d_in[6];
    const float* out_proj_w   = (const float*)d_in[7];
    const float* out_proj_b   = (const float*)d_in[8];
    const float* samp_off_w   = (const float*)d_in[9];
    const float* samp_off_b   = (const float*)d_in[10];
    const float* attn_w_w     = (const float*)d_in[11];
    const float* attn_w_b     = (const float*)d_in[12];
    const float* value_proj_w = (const float*)d_in[13];
    const float* value_proj_b = (const float*)d_in[14];
    const float* cross_out_w  = (const float*)d_in[15];
    const float* cross_out_b  = (const float*)d_in[16];
    const float* ln1_g = (const float*)d_in[17];
    const float* ln1_b = (const float*)d_in[18];
    const float* ln2_g = (const float*)d_in[19];
    const float* ln2_b = (const float*)d_in[20];
    const float* ln3_g = (const float*)d_in[21];
    const float* ln3_b = (const float*)d_in[22];
    const float* ffn_w1 = (const float*)d_in[23];
    const float* ffn_b1 = (const float*)d_in[24];
    const float* ffn_w2 = (const float*)d_in[25];
    const float* ffn_b2 = (const float*)d_in[26];
    float* out = (float*)d_out;

    // ---- fp32 arena (floats) ----
    float* ws    = (float*)d_ws;
    float* t     = ws;                    // residual; later ff
    float* ff    = ws;
    float* sa    = ws + 7372800;          // self-attn proj; later t2
    float* t2    = sa;
    float* comb  = ws + 14745600;         // 28800x288 off+aw -> msprep packed; later cross
    float* cross = comb;
    float* qpv   = ws + 23040000;         // 1056 qp-proj + 288 cbias
    float* cbias = qpv + 1056;

    // ---- bf16 arena (ushort), after fp32 arena (byte 92,165,376) ----
    unsigned short* bws    = (unsigned short*)((char*)d_ws + 92165376);
    unsigned short* s1     = bws;                  // tgtb -> ctxb -> tb -> t2b
    unsigned short* tgtb   = s1;
    unsigned short* ctxb   = s1;
    unsigned short* tb     = s1;
    unsigned short* t2b    = s1;
    unsigned short* s2     = bws + 7372800;        // qkvb / valueb+msoutb / hiddenb
    unsigned short* qkvb   = s2;
    unsigned short* valueb = s2;
    unsigned short* msoutb = s2 + 9676800;
    unsigned short* hiddenb= s2;
    unsigned short* srcb   = bws + 36864000;
    unsigned short* wtsb   = bws + 46540800;       // 991,232 shorts

    // 1. conversions
    conv_f2b_kernel<<<7200, 256, 0, stream>>>(tgt, tgtb, 1843200);
    conv_f2b_kernel<<<9450, 256, 0, stream>>>(src, srcb, 2419200);
    qp_proj_kernel<<<5, 256, 0, stream>>>(qp, in_proj_w, samp_off_w, attn_w_w,
                                          samp_off_b, attn_w_b, qpv);
    wconvert_kernel<<<968, 256, 0, stream>>>(in_proj_w, out_proj_w, value_proj_w,
                                             cross_out_w, samp_off_w, attn_w_w,
                                             ffn_w1, ffn_w2, wtsb);
    // 2. QKV projection (Q,K rows get query_pos bias via qpv, cols < 512)
    gemm_bf16<<<dim3(225, 6), 256, 0, stream>>>(tgtb, wtsb + 0, in_proj_b, qpv, 512,
                                                nullptr, qkvb, MROWS, 768, 256, 0);
    // 3. self-attention over batch axis
    self_attn_kernel<<<3600, 256, 0, stream>>>(qkvb, ctxb);
    // 4. out_proj
    gemm_bf16<<<dim3(225, 2), 256, 0, stream>>>(ctxb, wtsb + 196608, out_proj_b, nullptr, 0,
                                                sa, nullptr, MROWS, 256, 256, 0);
    // 5. t = LN2(tgt + sa)
    add_ln_kernel<<<7200, 256, 0, stream>>>(tgt, sa, ln2_g, ln2_b, t, tb);
    // 6. value projection (M = 37800)
    gemm_bf16<<<dim3(296, 2), 256, 0, stream>>>(srcb, wtsb + 262144, value_proj_b, nullptr, 0,
                                                nullptr, valueb, BATCH * LIN, 256, 256, 0);
    // 7. fused sampling-offset + attn-weight projection (N = 288)
    gemm_bf16<<<dim3(225, 3), 256, 0, stream>>>(tb, wtsb + 393216, cbias, nullptr, 0,
                                                comb, nullptr, MROWS, 288, 256, 0);
    // 8a. precompute packed sampling metadata (in place over comb)
    msprep_kernel<<<900, 256, 0, stream>>>(comb);
    // 8b. deformable sampling (hot)
    msdeform_kernel<<<7200, 256, 0, stream>>>(valueb, (const unsigned int*)comb, msoutb);
    // 9. cross output projection
    gemm_bf16<<<dim3(225, 2), 256, 0, stream>>>(msoutb, wtsb + 327680, cross_out_b, nullptr, 0,
                                                cross, nullptr, MROWS, 256, 256, 0);
    // 10. t2 = LN1(t + cross)
    add_ln_kernel<<<7200, 256, 0, stream>>>(t, cross, ln1_g, ln1_b, t2, t2b);
    // 11. FFN layer 1 (+ReLU), bf16 out
    gemm_bf16<<<dim3(225, 8), 256, 0, stream>>>(t2b, wtsb + 466944, ffn_b1, nullptr, 0,
                                                nullptr, hiddenb, MROWS, DFF, 256, 1);
    // 12. FFN layer 2
    gemm_bf16<<<dim3(225, 2), 256, 0, stream>>>(hiddenb, wtsb + 729088, ffn_b2, nullptr, 0,
                                                ff, nullptr, MROWS, 256, DFF, 0);
    // 13. out = LN3(t2 + ff)
    add_ln_kernel<<<7200, 256, 0, stream>>>(t2, ff, ln3_g, ln3_b, out, nullptr);
}

// Round 4
// 472.642 us; speedup vs baseline: 2.8494x; 1.1070x over previous
//
#include <hip/hip_runtime.h>
#include <hip/hip_bf16.h>
#include <cstddef>
#include <cstdint>

// Problem constants
#define D_MODEL 256
#define NHEAD   8
#define HDIM    32
#define NLEV    3
#define NPNT    4
#define DFF     1024
#define BATCH   8
#define LQ      3600
#define LIN     4725   // 60*60 + 30*30 + 15*15
#define MROWS   (BATCH*LQ)   // 28800; row order is (lq,b): m = lq*8 + b

typedef short bf16x8 __attribute__((ext_vector_type(8)));
typedef float f32x4  __attribute__((ext_vector_type(4)));

__device__ __forceinline__ unsigned short f2b(float x) {
    unsigned int u = __float_as_uint(x);
    unsigned int r = (u + 0x7fffu + ((u >> 16) & 1u)) >> 16;   // RNE
    return (unsigned short)r;
}
__device__ __forceinline__ float b2f(unsigned short s) {
    return __uint_as_float(((unsigned int)s) << 16);
}

#define GLDS16(g, l) __builtin_amdgcn_global_load_lds( \
    (const __attribute__((address_space(1))) void*)(g), \
    (__attribute__((address_space(3))) void*)(l), 16, 0, 0)

// ---------------------------------------------------------------------------
// Merged prep: [0,7200) conv tgt->bf16; [7200,16650) conv src->bf16;
// [16650,17618) weight convert; [17618,17623) query_pos projections.
#define WTOT 991232
__global__ __launch_bounds__(256) void prep_kernel(
    const float* __restrict__ tgt, unsigned short* __restrict__ tgtb,
    const float* __restrict__ srcf, unsigned short* __restrict__ srcb,
    const float* __restrict__ w_in, const float* __restrict__ w_out,
    const float* __restrict__ w_val, const float* __restrict__ w_cross,
    const float* __restrict__ w_so, const float* __restrict__ w_aw,
    const float* __restrict__ w_f1, const float* __restrict__ w_f2,
    unsigned short* __restrict__ wdst,
    const float* __restrict__ qp, const float* __restrict__ so_b,
    const float* __restrict__ aw_b, float* __restrict__ qpv)
{
    const int bid = blockIdx.x;
    const int tid = threadIdx.x;
    if (bid < 7200) {
        int i = bid * 256 + tid;                      // < 1843200 exactly
        float4 v = ((const float4*)tgt)[i];
        ushort4 o; o.x = f2b(v.x); o.y = f2b(v.y); o.z = f2b(v.z); o.w = f2b(v.w);
        ((ushort4*)tgtb)[i] = o;
    } else if (bid < 16650) {
        int i = (bid - 7200) * 256 + tid;             // < 2419200 exactly
        float4 v = ((const float4*)srcf)[i];
        ushort4 o; o.x = f2b(v.x); o.y = f2b(v.y); o.z = f2b(v.z); o.w = f2b(v.w);
        ((ushort4*)srcb)[i] = o;
    } else if (bid < 17618) {
        int idx = ((bid - 16650) * 256 + tid) * 4;
        if (idx >= WTOT) return;
        const float* src; int off;
        if      (idx < 196608) { src = w_in;    off = idx; }
        else if (idx < 262144) { src = w_out;   off = idx - 196608; }
        else if (idx < 327680) { src = w_val;   off = idx - 262144; }
        else if (idx < 393216) { src = w_cross; off = idx - 327680; }
        else if (idx < 442368) { src = w_so;    off = idx - 393216; }
        else if (idx < 466944) { src = w_aw;    off = idx - 442368; }
        else if (idx < 729088) { src = w_f1;    off = idx - 466944; }
        else                   { src = w_f2;    off = idx - 729088; }
        float4 v = *(const float4*)(src + off);
        ushort4 o; o.x = f2b(v.x); o.y = f2b(v.y); o.z = f2b(v.z); o.w = f2b(v.w);
        *(ushort4*)(wdst + idx) = o;
    } else {
        int o = (bid - 17618) * 256 + tid;
        if (o >= 768 + 192 + 96) return;
        const float* wrow;
        if (o < 768)       wrow = w_in + (size_t)o * D_MODEL;
        else if (o < 960)  wrow = w_so + (size_t)(o - 768) * D_MODEL;
        else               wrow = w_aw + (size_t)(o - 960) * D_MODEL;
        float acc = 0.f;
        for (int d = 0; d < D_MODEL; ++d) acc += qp[d] * wrow[d];
        qpv[o] = acc;
        if (o >= 768) {
            float bias = (o < 960) ? so_b[o - 768] : aw_b[o - 960];
            qpv[1056 + (o - 768)] = acc + bias;
        }
    }
}

// ---------------------------------------------------------------------------
// bf16 MFMA GEMM, 128x128 tile, BK=64 as 2x32 panels per barrier pair.
// K must be divisible by 64 (all uses: K=256).
__global__ __launch_bounds__(256) void gemm_bf16(
    const unsigned short* __restrict__ A,
    const unsigned short* __restrict__ W,
    const float* __restrict__ bias,
    const float* __restrict__ bias2, int b2lim,
    float* __restrict__ Cf, unsigned short* __restrict__ Cb,
    int M, int N, int K, int relu)
{
    __shared__ __align__(16) unsigned short As[2 * 128 * 32];   // 16 KB
    __shared__ __align__(16) unsigned short Bs[2 * 128 * 32];   // 16 KB
    const int tid  = threadIdx.x;
    const int wave = tid >> 6;
    const int lane = tid & 63;
    const int m0 = blockIdx.x * 128;
    const int n0 = blockIdx.y * 128;

    const int lr  = lane >> 2;
    const int lc8 = (lane & 3) * 8;
    int ar0 = m0 + wave * 32 + lr;      if (ar0 > M - 1) ar0 = M - 1;
    int ar1 = m0 + wave * 32 + 16 + lr; if (ar1 > M - 1) ar1 = M - 1;
    int br0 = n0 + wave * 32 + lr;      if (br0 > N - 1) br0 = N - 1;
    int br1 = n0 + wave * 32 + 16 + lr; if (br1 > N - 1) br1 = N - 1;
    const unsigned short* pa0 = A + (size_t)ar0 * K + lc8;
    const unsigned short* pa1 = A + (size_t)ar1 * K + lc8;
    const unsigned short* pb0 = W + (size_t)br0 * K + lc8;
    const unsigned short* pb1 = W + (size_t)br1 * K + lc8;
    unsigned short* la0 = As + wave * 1024;
    unsigned short* la1 = As + wave * 1024 + 512;
    unsigned short* lb0 = Bs + wave * 1024;
    unsigned short* lb1 = Bs + wave * 1024 + 512;

    const int wm = (wave >> 1) * 64;
    const int wn = (wave & 1) * 64;
    const int fr = lane & 15;
    const int fk = (lane >> 4) * 8;

    f32x4 acc[4][4] = {};

    for (int k0 = 0; k0 < K; k0 += 64) {
        GLDS16(pa0, la0); GLDS16(pa0 + 32, la0 + 4096);
        GLDS16(pa1, la1); GLDS16(pa1 + 32, la1 + 4096);
        GLDS16(pb0, lb0); GLDS16(pb0 + 32, lb0 + 4096);
        GLDS16(pb1, lb1); GLDS16(pb1 + 32, lb1 + 4096);
        pa0 += 64; pa1 += 64; pb0 += 64; pb1 += 64;
        __syncthreads();
#pragma unroll
        for (int p = 0; p < 2; ++p) {
            bf16x8 af[4], bfv[4];
#pragma unroll
            for (int i = 0; i < 4; ++i)
                af[i] = *(const bf16x8*)&As[p * 4096 + (wm + i * 16 + fr) * 32 + fk];
#pragma unroll
            for (int j = 0; j < 4; ++j)
                bfv[j] = *(const bf16x8*)&Bs[p * 4096 + (wn + j * 16 + fr) * 32 + fk];
#pragma unroll
            for (int i = 0; i < 4; ++i)
#pragma unroll
                for (int j = 0; j < 4; ++j)
                    acc[i][j] = __builtin_amdgcn_mfma_f32_16x16x32_bf16(
                        af[i], bfv[j], acc[i][j], 0, 0, 0);
        }
        __syncthreads();
    }

    const int quad = lane >> 4;
#pragma unroll
    for (int j = 0; j < 4; ++j) {
        const int col = n0 + wn + j * 16 + fr;
        if (col >= N) continue;
        float bv = 0.f;
        if (bias) bv += bias[col];
        if (bias2 && col < b2lim) bv += bias2[col];
#pragma unroll
        for (int i = 0; i < 4; ++i) {
#pragma unroll
            for (int r = 0; r < 4; ++r) {
                const int row = m0 + wm + i * 16 + quad * 4 + r;
                if (row >= M) continue;
                float v = acc[i][j][r] + bv;
                if (relu) v = fmaxf(v, 0.f);
                if (Cf) Cf[(size_t)row * N + col] = v;
                if (Cb) Cb[(size_t)row * N + col] = f2b(v);
            }
        }
    }
}

// ---------------------------------------------------------------------------
// GEMM (N=256 fixed, full row per block) + residual add + LayerNorm fused.
// Block = 64 rows x 256 cols; wave w computes cols w*64..w*64+63 of all rows.
// outf[row] = LN(gemm+bias+resid) * g + bb  (fp32), optional bf16 copy outb.
// In-place safe when A rows alias outb rows (block reads its own A rows
// fully, barrier-ordered, before the epilogue writes them).
__global__ __launch_bounds__(256) void gemm_ln(
    const unsigned short* __restrict__ A,    // M x K bf16
    const unsigned short* __restrict__ W,    // 256 x K bf16
    const float* __restrict__ bias,          // 256
    const float* __restrict__ resid,         // M x 256 fp32
    const float* __restrict__ g, const float* __restrict__ bb,
    float* __restrict__ outf, unsigned short* __restrict__ outb, int K)
{
    __shared__ __align__(16) unsigned short As[2 * 64 * 32];    // 8 KB
    __shared__ __align__(16) unsigned short Bs[2 * 256 * 32];   // 32 KB
    const int tid  = threadIdx.x;
    const int wave = tid >> 6;
    const int lane = tid & 63;
    const int m0 = blockIdx.x * 64;

    const int arow = tid >> 2;
    const int akc  = (tid & 3) * 8;
    const unsigned short* pa = A + (size_t)(m0 + arow) * K + akc;
    unsigned short* la = As + tid * 8;
    const unsigned short* pb0 = W + (size_t)(arow)       * K + akc;
    const unsigned short* pb1 = W + (size_t)(64  + arow) * K + akc;
    const unsigned short* pb2 = W + (size_t)(128 + arow) * K + akc;
    const unsigned short* pb3 = W + (size_t)(192 + arow) * K + akc;
    unsigned short* lb0 = Bs + tid * 8;
    unsigned short* lb1 = Bs + 2048 + tid * 8;
    unsigned short* lb2 = Bs + 4096 + tid * 8;
    unsigned short* lb3 = Bs + 6144 + tid * 8;

    const int fr = lane & 15;
    const int fk = (lane >> 4) * 8;
    const int quad = lane >> 4;
    const int colbase = wave * 64;

    f32x4 acc[4][4] = {};

    for (int k0 = 0; k0 < K; k0 += 64) {
        GLDS16(pa, la);        GLDS16(pa + 32, la + 2048);
        GLDS16(pb0, lb0);      GLDS16(pb0 + 32, lb0 + 8192);
        GLDS16(pb1, lb1);      GLDS16(pb1 + 32, lb1 + 8192);
        GLDS16(pb2, lb2);      GLDS16(pb2 + 32, lb2 + 8192);
        GLDS16(pb3, lb3);      GLDS16(pb3 + 32, lb3 + 8192);
        pa += 64; pb0 += 64; pb1 += 64; pb2 += 64; pb3 += 64;
        __syncthreads();
#pragma unroll
        for (int p = 0; p < 2; ++p) {
            bf16x8 af[4], bfv[4];
#pragma unroll
            for (int i = 0; i < 4; ++i)
                af[i] = *(const bf16x8*)&As[p * 2048 + (i * 16 + fr) * 32 + fk];
#pragma unroll
            for (int j = 0; j < 4; ++j)
                bfv[j] = *(const bf16x8*)&Bs[p * 8192 + (colbase + j * 16 + fr) * 32 + fk];
#pragma unroll
            for (int i = 0; i < 4; ++i)
#pragma unroll
                for (int j = 0; j < 4; ++j)
                    acc[i][j] = __builtin_amdgcn_mfma_f32_16x16x32_bf16(
                        af[i], bfv[j], acc[i][j], 0, 0, 0);
        }
        __syncthreads();
    }

    // ---- fused epilogue: v = acc + bias + resid; LN over 256 cols ----
    float2* red = (float2*)As;   // 256 entries [wave*64 + rowlocal]; aliases As
    float rs[4][4], rq[4][4];
#pragma unroll
    for (int i = 0; i < 4; ++i) {
#pragma unroll
        for (int r = 0; r < 4; ++r) {
            const int row = m0 + i * 16 + quad * 4 + r;
            float s = 0.f, q = 0.f;
#pragma unroll
            for (int j = 0; j < 4; ++j) {
                const int col = colbase + j * 16 + fr;
                float v = acc[i][j][r] + bias[col] + resid[(size_t)row * 256 + col];
                acc[i][j][r] = v;
                s += v; q += v * v;
            }
            rs[i][r] = s; rq[i][r] = q;
        }
    }
#pragma unroll
    for (int off = 1; off < 16; off <<= 1) {
#pragma unroll
        for (int i = 0; i < 4; ++i)
#pragma unroll
            for (int r = 0; r < 4; ++r) {
                rs[i][r] += __shfl_xor(rs[i][r], off);
                rq[i][r] += __shfl_xor(rq[i][r], off);
            }
    }
    if ((lane & 15) == 0) {
#pragma unroll
        for (int i = 0; i < 4; ++i)
#pragma unroll
            for (int r = 0; r < 4; ++r)
                red[wave * 64 + i * 16 + quad * 4 + r] = make_float2(rs[i][r], rq[i][r]);
    }
    __syncthreads();
#pragma unroll
    for (int i = 0; i < 4; ++i) {
#pragma unroll
        for (int r = 0; r < 4; ++r) {
            const int rl = i * 16 + quad * 4 + r;
            const float2 t0 = red[rl], t1 = red[64 + rl], t2 = red[128 + rl], t3 = red[192 + rl];
            const float sum = t0.x + t1.x + t2.x + t3.x;
            const float sq  = t0.y + t1.y + t2.y + t3.y;
            const float mean = sum * (1.f / 256.f);
            const float var  = sq * (1.f / 256.f) - mean * mean;
            const float inv  = rsqrtf(var + 1e-5f);
            const int row = m0 + rl;
#pragma unroll
            for (int j = 0; j < 4; ++j) {
                const int col = colbase + j * 16 + fr;
                const float val = (acc[i][j][r] - mean) * inv * g[col] + bb[col];
                outf[(size_t)row * 256 + col] = val;
                if (outb) outb[(size_t)row * 256 + col] = f2b(val);
            }
        }
    }
}

// ---------------------------------------------------------------------------
// Self-attention over S=8 (batch axis). Row order (lq,b): row = n*8 + s.
__global__ __launch_bounds__(256) void self_attn_kernel(
    const unsigned short* __restrict__ qkv, unsigned short* __restrict__ ctx)
{
    __shared__ float sh[8][768];
    __shared__ float ls[8][8][8];   // [h][s][t]
    const int n = blockIdx.x;
    const int t = threadIdx.x;
#pragma unroll
    for (int s = 0; s < 8; ++s) {
        const unsigned short* row = qkv + (size_t)(n * 8 + s) * 768;
        sh[s][t]       = b2f(row[t]);
        sh[s][t + 256] = b2f(row[t + 256]);
        sh[s][t + 512] = b2f(row[t + 512]);
    }
    __syncthreads();
    const int h = t >> 5, j = t & 31;
#pragma unroll
    for (int pair = j; pair < 64; pair += 32) {
        const int s = pair >> 3, tt = pair & 7;
        float acc = 0.f;
#pragma unroll
        for (int d = 0; d < 32; ++d)
            acc += sh[s][h * 32 + d] * sh[tt][256 + h * 32 + d];
        ls[h][s][tt] = acc * 0.17677669529663687f;
    }
    __syncthreads();
    if (t < 64) {
        const int hh = t >> 3, s = t & 7;
        float mx = -1e30f;
        for (int tt = 0; tt < 8; ++tt) mx = fmaxf(mx, ls[hh][s][tt]);
        float sum = 0.f;
        for (int tt = 0; tt < 8; ++tt) { float e = expf(ls[hh][s][tt] - mx); ls[hh][s][tt] = e; sum += e; }
        const float inv = 1.f / sum;
        for (int tt = 0; tt < 8; ++tt) ls[hh][s][tt] *= inv;
    }
    __syncthreads();
#pragma unroll
    for (int s = 0; s < 8; ++s) {
        float acc = 0.f;
#pragma unroll
        for (int tt = 0; tt < 8; ++tt)
            acc += ls[h][s][tt] * sh[tt][512 + h * 32 + j];
        ctx[(size_t)(n * 8 + s) * D_MODEL + h * 32 + j] = f2b(acc);
    }
}

// ---------------------------------------------------------------------------
// msprep: one thread per (m,h); softmax + bilinear setup once, packed 12 B/pt,
// written in place over comb rows (whole rows per block; barrier between).
__global__ __launch_bounds__(256) void msprep_kernel(float* __restrict__ comb)
{
    const int tid = threadIdx.x;
    const int m = blockIdx.x * 32 + (tid >> 3);
    const int h = tid & 7;
    const int lq = m >> 3;
    const float* offp = comb + (size_t)m * 288 + h * 24;
    const float* awp  = comb + (size_t)m * 288 + 192 + h * 12;
    float off[24], aw[12];
#pragma unroll
    for (int i = 0; i < 6; ++i) *(float4*)&off[i * 4] = ((const float4*)offp)[i];
#pragma unroll
    for (int i = 0; i < 3; ++i) *(float4*)&aw[i * 4] = ((const float4*)awp)[i];

    float mx = aw[0];
#pragma unroll
    for (int i = 1; i < 12; ++i) mx = fmaxf(mx, aw[i]);
    float se = 0.f;
#pragma unroll
    for (int i = 0; i < 12; ++i) { aw[i] = __expf(aw[i] - mx); se += aw[i]; }
    const float inv = 1.f / se;

    const float refx = ((lq % 60) + 0.5f) * (1.f / 60.f);
    const float refy = ((lq / 60) + 0.5f) * (1.f / 60.f);
    const int HW[3] = {60, 30, 15};
    const int ST[3] = {0, 3600, 4500};

    unsigned int outv[36];
#pragma unroll
    for (int lev = 0; lev < NLEV; ++lev) {
        const int Wl = HW[lev], Hl = HW[lev], s0 = ST[lev];
        const float fWl = (float)Wl, fHl = (float)Hl;
#pragma unroll
        for (int p = 0; p < NPNT; ++p) {
            const int pt = lev * 4 + p;
            const float ox = off[lev * 8 + p * 2];
            const float oy = off[lev * 8 + p * 2 + 1];
            const float px = refx * fWl + ox - 0.5f;
            const float py = refy * fHl + oy - 0.5f;
            const float x0f = floorf(px), y0f = floorf(py);
            const float fx = px - x0f, fy = py - y0f;
            const int x0 = (int)x0f, y0 = (int)y0f;
            const float aww = aw[pt] * inv;
            const float vx0 = (x0 >= 0 && x0 < Wl) ? 1.f : 0.f;
            const float vx1 = (x0 >= -1 && x0 < Wl - 1) ? 1.f : 0.f;
            const float vy0 = (y0 >= 0 && y0 < Hl) ? 1.f : 0.f;
            const float vy1 = (y0 >= -1 && y0 < Hl - 1) ? 1.f : 0.f;
            const int xc0 = min(max(x0, 0), Wl - 1);
            const int xc1 = min(max(x0 + 1, 0), Wl - 1);
            const int yc0 = min(max(y0, 0), Hl - 1);
            const int yc1 = min(max(y0 + 1, 0), Hl - 1);
            const unsigned int sx  = (unsigned int)(xc1 - xc0);
            const unsigned int syW = (unsigned int)((yc1 - yc0) * Wl);
            const unsigned int idx = (unsigned int)(s0 + yc0 * Wl + xc0);
            const float w00 = (1.f - fx) * (1.f - fy) * aww * vx0 * vy0;
            const float w01 = fx * (1.f - fy) * aww * vx1 * vy0;
            const float w10 = (1.f - fx) * fy * aww * vx0 * vy1;
            const float w11 = fx * fy * aww * vx1 * vy1;
            outv[pt * 3]     = idx | (sx << 16) | (syW << 17);
            outv[pt * 3 + 1] = (unsigned int)f2b(w00) | ((unsigned int)f2b(w01) << 16);
            outv[pt * 3 + 2] = (unsigned int)f2b(w10) | ((unsigned int)f2b(w11) << 16);
        }
    }
    __syncthreads();
    uint4* dst = (uint4*)((char*)comb + (size_t)m * 1152 + h * 144);
#pragma unroll
    for (int i = 0; i < 9; ++i) dst[i] = *(uint4*)&outv[i * 4];
}

// ---------------------------------------------------------------------------
// Hot deformable sampling (unchanged from R3).
__global__ __launch_bounds__(256) void msdeform_kernel(
    const unsigned short* __restrict__ value,
    const unsigned int* __restrict__ meta,
    unsigned short* __restrict__ out)
{
    const int bid = blockIdx.x;
    const int b   = bid & 7;
    const int lq0 = (bid >> 3) * 4;
    const int r    = threadIdx.x >> 6;
    const int lane = threadIdx.x & 63;
    const int h = lane >> 3;
    const int l = lane & 7;
    const int m = (lq0 + r) * 8 + b;

    const unsigned int* mp = meta + (size_t)m * 288 + h * 36;
    uint4 md[9];
#pragma unroll
    for (int i = 0; i < 9; ++i) md[i] = ((const uint4*)mp)[i];
    const unsigned int* mw = (const unsigned int*)md;

    const unsigned short* vbase = value + (size_t)b * LIN * 256 + h * 32 + l * 4;

    float a0 = 0.f, a1 = 0.f, a2 = 0.f, a3 = 0.f;
#pragma unroll
    for (int p = 0; p < 12; ++p) {
        const unsigned int pack = mw[p * 3];
        const unsigned int wlo  = mw[p * 3 + 1];
        const unsigned int whi  = mw[p * 3 + 2];
        const unsigned int i00 = pack & 0xFFFFu;
        const unsigned int sx  = (pack >> 16) & 1u;
        const unsigned int syW = pack >> 17;
        const unsigned int i01 = i00 + sx;
        const unsigned int i10 = i00 + syW;
        const unsigned int i11 = i10 + sx;
        const float w00 = __uint_as_float(wlo << 16);
        const float w01 = __uint_as_float(wlo & 0xFFFF0000u);
        const float w10 = __uint_as_float(whi << 16);
        const float w11 = __uint_as_float(whi & 0xFFFF0000u);
        const ushort4 g00 = *(const ushort4*)(vbase + (size_t)i00 * 256);
        const ushort4 g01 = *(const ushort4*)(vbase + (size_t)i01 * 256);
        const ushort4 g10 = *(const ushort4*)(vbase + (size_t)i10 * 256);
        const ushort4 g11 = *(const ushort4*)(vbase + (size_t)i11 * 256);
        a0 += b2f(g00.x) * w00 + b2f(g01.x) * w01 + b2f(g10.x) * w10 + b2f(g11.x) * w11;
        a1 += b2f(g00.y) * w00 + b2f(g01.y) * w01 + b2f(g10.y) * w10 + b2f(g11.y) * w11;
        a2 += b2f(g00.z) * w00 + b2f(g01.z) * w01 + b2f(g10.z) * w10 + b2f(g11.z) * w11;
        a3 += b2f(g00.w) * w00 + b2f(g01.w) * w01 + b2f(g10.w) * w10 + b2f(g11.w) * w11;
    }
    ushort4 o;
    o.x = f2b(a0); o.y = f2b(a1); o.z = f2b(a2); o.w = f2b(a3);
    *(ushort4*)(out + (size_t)m * 256 + h * 32 + l * 4) = o;
}

// ---------------------------------------------------------------------------
extern "C" void kernel_launch(void* const* d_in, const int* in_sizes, int n_in,
                              void* d_out, int out_size, void* d_ws, size_t ws_size,
                              hipStream_t stream)
{
    (void)in_sizes; (void)n_in; (void)out_size; (void)ws_size;
    const float* tgt          = (const float*)d_in[0];   // (LQ,B,D): (lq,b)-major rows
    const float* qp           = (const float*)d_in[1];
    const float* src          = (const float*)d_in[2];
    const float* in_proj_w    = (const float*)d_in[5];
    const float* in_proj_b    = (const float*)d_in[6];
    const float* out_proj_w   = (const float*)d_in[7];
    const float* out_proj_b   = (const float*)d_in[8];
    const float* samp_off_w   = (const float*)d_in[9];
    const float* samp_off_b   = (const float*)d_in[10];
    const float* attn_w_w     = (const float*)d_in[11];
    const float* attn_w_b     = (const float*)d_in[12];
    const float* value_proj_w = (const float*)d_in[13];
    const float* value_proj_b = (const float*)d_in[14];
    const float* cross_out_w  = (const float*)d_in[15];
    const float* cross_out_b  = (const float*)d_in[16];
    const float* ln1_g = (const float*)d_in[17];
    const float* ln1_b = (const float*)d_in[18];
    const float* ln2_g = (const float*)d_in[19];
    const float* ln2_b = (const float*)d_in[20];
    const float* ln3_g = (const float*)d_in[21];
    const float* ln3_b = (const float*)d_in[22];
    const float* ffn_w1 = (const float*)d_in[23];
    const float* ffn_b1 = (const float*)d_in[24];
    const float* ffn_w2 = (const float*)d_in[25];
    const float* ffn_b2 = (const float*)d_in[26];
    float* out = (float*)d_out;

    // ---- fp32 arena (floats) ----
    float* ws    = (float*)d_ws;
    float* t     = ws;                    // LN2 out (residual for LN1)
    float* t2    = ws + 7372800;          // LN1 out (residual for LN3)
    float* comb  = ws + 14745600;         // 28800x288 off+aw -> msprep packed
    float* qpv   = ws + 23040000;         // 1056 qp-proj + 288 cbias
    float* cbias = qpv + 1056;

    // ---- bf16 arena (ushort), after fp32 arena (byte 92,165,376) ----
    unsigned short* bws    = (unsigned short*)((char*)d_ws + 92165376);
    unsigned short* s1     = bws;                  // tgtb -> ctxb -> tb -> t2b
    unsigned short* tgtb   = s1;
    unsigned short* ctxb   = s1;
    unsigned short* tb     = s1;
    unsigned short* t2b    = s1;
    unsigned short* s2     = bws + 7372800;        // qkvb / valueb+msoutb / hiddenb
    unsigned short* qkvb   = s2;
    unsigned short* valueb = s2;
    unsigned short* msoutb = s2 + 9676800;
    unsigned short* hiddenb= s2;
    unsigned short* srcb   = bws + 36864000;
    unsigned short* wtsb   = bws + 46540800;       // 991,232 shorts

    // 1. merged prep (conversions + weight cast + query_pos projections)
    prep_kernel<<<17623, 256, 0, stream>>>(tgt, tgtb, src, srcb,
                                           in_proj_w, out_proj_w, value_proj_w,
                                           cross_out_w, samp_off_w, attn_w_w,
                                           ffn_w1, ffn_w2, wtsb,
                                           qp, samp_off_b, attn_w_b, qpv);
    // 2. QKV projection (Q,K cols get query_pos bias via qpv, cols < 512)
    gemm_bf16<<<dim3(225, 6), 256, 0, stream>>>(tgtb, wtsb + 0, in_proj_b, qpv, 512,
                                                nullptr, qkvb, MROWS, 768, 256, 0);
    // 3. self-attention over batch axis
    self_attn_kernel<<<3600, 256, 0, stream>>>(qkvb, ctxb);
    // 4. t = LN2(tgt + out_proj(ctx))   [fused; in-place ctxb->tb safe]
    gemm_ln<<<450, 256, 0, stream>>>(ctxb, wtsb + 196608, out_proj_b, tgt,
                                     ln2_g, ln2_b, t, tb, 256);
    // 5. value projection (M = 37800)
    gemm_bf16<<<dim3(296, 2), 256, 0, stream>>>(srcb, wtsb + 262144, value_proj_b, nullptr, 0,
                                                nullptr, valueb, BATCH * LIN, 256, 256, 0);
    // 6. fused sampling-offset + attn-weight projection (N = 288)
    gemm_bf16<<<dim3(225, 3), 256, 0, stream>>>(tb, wtsb + 393216, cbias, nullptr, 0,
                                                comb, nullptr, MROWS, 288, 256, 0);
    // 7. packed sampling metadata (in place over comb)
    msprep_kernel<<<900, 256, 0, stream>>>(comb);
    // 8. deformable sampling (hot)
    msdeform_kernel<<<7200, 256, 0, stream>>>(valueb, (const unsigned int*)comb, msoutb);
    // 9. t2 = LN1(t + cross_out(msout))   [fused]
    gemm_ln<<<450, 256, 0, stream>>>(msoutb, wtsb + 327680, cross_out_b, t,
                                     ln1_g, ln1_b, t2, t2b, 256);
    // 10. FFN layer 1 (+ReLU), bf16 out
    gemm_bf16<<<dim3(225, 8), 256, 0, stream>>>(t2b, wtsb + 466944, ffn_b1, nullptr, 0,
                                                nullptr, hiddenb, MROWS, DFF, 256, 1);
    // 11. out = LN3(t2 + ffn2(hidden))   [fused; K=1024]
    gemm_ln<<<450, 256, 0, stream>>>(hiddenb, wtsb + 729088, ffn_b2, t2,
                                     ln3_g, ln3_b, out, nullptr, 1024);
}